// Round 1
// baseline (567.776 us; speedup 1.0000x reference)
//
#include <hip/hip_runtime.h>
#include <hip/hip_bf16.h>

typedef __bf16 bf16_t;
typedef __bf16 bf16x8 __attribute__((ext_vector_type(8)));
typedef __bf16 bf16x4 __attribute__((ext_vector_type(4)));
typedef float f32x4 __attribute__((ext_vector_type(4)));

#define B_DIM 4
#define NQ 2048
#define NK 2048
#define DMODEL 1024
#define NH 8
#define DHEAD 128

// ---------------------------------------------------------------------------
// GEMM NT: C[M,N] = A[M,K] (fp32) * B[N,K]^T (fp32) + bias, bf16 MFMA compute.
// MODE 0: bf16 row-major out (Cb)
// MODE 1: fp32 out  Cf = resid + relu(acc + bias)
// MODE 2: bf16 transposed scatter into vT[b][h][d][NK]
// ---------------------------------------------------------------------------
template <int MODE>
__global__ __launch_bounds__(256) void gemm_nt(
    const float* __restrict__ A, const float* __restrict__ Bm,
    const float* __restrict__ bias, const float* __restrict__ resid,
    bf16_t* __restrict__ Cb, float* __restrict__ Cf,
    int M, int N, int K)
{
    const int tid  = threadIdx.x;
    const int lane = tid & 63;
    const int wv   = tid >> 6;
    const int l16  = lane & 15;
    const int quad = (lane >> 4) & 3;
    const int wr   = wv >> 1, wc = wv & 1;
    const int rowBase = blockIdx.y * 128;
    const int colBase = blockIdx.x * 128;

    // LDS tiles, 128 rows x 32 k, stride 40 elems (80B) to dodge bank conflicts
    __shared__ bf16_t sA[128 * 40];
    __shared__ bf16_t sB[128 * 40];

    const f32x4 fzero = {0.f, 0.f, 0.f, 0.f};
    f32x4 acc[4][4];
#pragma unroll
    for (int i = 0; i < 4; i++)
#pragma unroll
        for (int j = 0; j < 4; j++) acc[i][j] = fzero;

    for (int k0 = 0; k0 < K; k0 += 32) {
        // stage A and B tiles: 128x32 fp32 each; 256 threads x 4 float4 per tile
#pragma unroll
        for (int i = 0; i < 4; i++) {
            int f  = tid + 256 * i;
            int r  = f >> 3;      // 8 float4 per row
            int c4 = f & 7;
            float4 av = *(const float4*)(A + (size_t)(rowBase + r) * K + k0 + c4 * 4);
            float4 bv = *(const float4*)(Bm + (size_t)(colBase + r) * K + k0 + c4 * 4);
            bf16x4 a4 = {(bf16_t)av.x, (bf16_t)av.y, (bf16_t)av.z, (bf16_t)av.w};
            bf16x4 b4 = {(bf16_t)bv.x, (bf16_t)bv.y, (bf16_t)bv.z, (bf16_t)bv.w};
            *(bf16x4*)(&sA[r * 40 + c4 * 4]) = a4;
            *(bf16x4*)(&sB[r * 40 + c4 * 4]) = b4;
        }
        __syncthreads();

        bf16x8 aF[4], bF[4];
#pragma unroll
        for (int mi = 0; mi < 4; mi++)
            aF[mi] = *(const bf16x8*)(&sA[(wr * 64 + mi * 16 + l16) * 40 + quad * 8]);
#pragma unroll
        for (int ni = 0; ni < 4; ni++)
            bF[ni] = *(const bf16x8*)(&sB[(wc * 64 + ni * 16 + l16) * 40 + quad * 8]);
#pragma unroll
        for (int mi = 0; mi < 4; mi++)
#pragma unroll
            for (int ni = 0; ni < 4; ni++)
                acc[mi][ni] = __builtin_amdgcn_mfma_f32_16x16x32_bf16(
                    aF[mi], bF[ni], acc[mi][ni], 0, 0, 0);
        __syncthreads();
    }

    // epilogue.  C/D layout: row = quad*4 + r, col = l16 within each 16x16 tile
#pragma unroll
    for (int mi = 0; mi < 4; mi++) {
#pragma unroll
        for (int ni = 0; ni < 4; ni++) {
            int row0 = rowBase + wr * 64 + mi * 16 + quad * 4;
            int col  = colBase + wc * 64 + ni * 16 + l16;
            float bv = bias[col];
            if (MODE == 0) {
#pragma unroll
                for (int r = 0; r < 4; r++)
                    Cb[(size_t)(row0 + r) * N + col] = (bf16_t)(acc[mi][ni][r] + bv);
            } else if (MODE == 1) {
#pragma unroll
                for (int r = 0; r < 4; r++) {
                    float v = acc[mi][ni][r] + bv;
                    v = v > 0.f ? v : 0.f;
                    Cf[(size_t)(row0 + r) * N + col] =
                        resid[(size_t)(row0 + r) * N + col] + v;
                }
            } else {
                // vT[b][h][dd][n]; rows of C are consecutive n -> pack 4 bf16
                int b  = row0 >> 11;        // NQ == 2048 rows per batch
                int n0 = row0 & 2047;
                int h  = col >> 7;          // DHEAD == 128
                int dd = col & 127;
                bf16x4 p = {(bf16_t)(acc[mi][ni][0] + bv), (bf16_t)(acc[mi][ni][1] + bv),
                            (bf16_t)(acc[mi][ni][2] + bv), (bf16_t)(acc[mi][ni][3] + bv)};
                *(bf16x4*)(Cb + (size_t)((b * NH + h) * DHEAD + dd) * NK + n0) = p;
            }
        }
    }
}

// ---------------------------------------------------------------------------
// Flash attention per (b,h): O = q + softmax(q k^T / sqrt(d)) v
// block = 256 threads = 4 waves; each wave owns 16 q-rows; 64 q-rows per block
// ---------------------------------------------------------------------------
__global__ __launch_bounds__(256) void attn_k(
    const bf16_t* __restrict__ qb, const bf16_t* __restrict__ kb,
    const bf16_t* __restrict__ vT, float* __restrict__ O)
{
    const int tid  = threadIdx.x;
    const int lane = tid & 63;
    const int wv   = tid >> 6;
    const int l16  = lane & 15;
    const int quad = (lane >> 4) & 3;
    const int qt   = blockIdx.x * 64;
    const int h    = blockIdx.y;
    const int b    = blockIdx.z;
    const int bh   = b * NH + h;

    __shared__ bf16_t sK[32 * 136];   // 32 keys x 128 d, stride 136
    __shared__ bf16_t sV[128 * 40];   // 128 d x 32 keys, stride 40
    __shared__ bf16_t sP[4][16 * 40]; // per-wave P tile 16 x 32, stride 40

    const int qrow = b * NQ + qt + wv * 16;
    bf16x8 qF[4];
#pragma unroll
    for (int c = 0; c < 4; c++)
        qF[c] = *(const bf16x8*)(qb + (size_t)(qrow + l16) * DMODEL + h * DHEAD + c * 32 + quad * 8);

    const f32x4 fzero = {0.f, 0.f, 0.f, 0.f};
    f32x4 accO[8];
#pragma unroll
    for (int d = 0; d < 8; d++) accO[d] = fzero;
    float mrow[4] = {-1e30f, -1e30f, -1e30f, -1e30f};
    float lrow[4] = {0.f, 0.f, 0.f, 0.f};
    const float scale = 0.08838834764831845f; // 1/sqrt(128)

    for (int kt = 0; kt < NK; kt += 32) {
        // cooperative staging of K (32x128) and V^T (128x32)
#pragma unroll
        for (int i = 0; i < 2; i++) {
            int f  = tid + 256 * i;
            int n  = f >> 4, c8 = f & 15;
            *(bf16x8*)(&sK[n * 136 + c8 * 8]) =
                *(const bf16x8*)(kb + (size_t)(b * NK + kt + n) * DMODEL + h * DHEAD + c8 * 8);
            int d = f >> 2, n8 = f & 3;
            *(bf16x8*)(&sV[d * 40 + n8 * 8]) =
                *(const bf16x8*)(vT + (size_t)(bh * DHEAD + d) * NK + kt + n8 * 8);
        }
        __syncthreads();

        // S = q k^T, two 16-col blocks
        f32x4 S[2];
#pragma unroll
        for (int cb = 0; cb < 2; cb++) {
            S[cb] = fzero;
#pragma unroll
            for (int c = 0; c < 4; c++) {
                bf16x8 kF = *(const bf16x8*)(&sK[(cb * 16 + l16) * 136 + c * 32 + quad * 8]);
                S[cb] = __builtin_amdgcn_mfma_f32_16x16x32_bf16(qF[c], kF, S[cb], 0, 0, 0);
            }
        }

        // online softmax
        float alpha[4];
#pragma unroll
        for (int r = 0; r < 4; r++) {
            float s0 = S[0][r] * scale, s1 = S[1][r] * scale;
            float mx = fmaxf(s0, s1);
#pragma unroll
            for (int msk = 1; msk < 16; msk <<= 1) mx = fmaxf(mx, __shfl_xor(mx, msk));
            float mnew = fmaxf(mrow[r], mx);
            alpha[r] = __expf(mrow[r] - mnew);
            mrow[r] = mnew;
            float p0 = __expf(s0 - mnew);
            float p1 = __expf(s1 - mnew);
            lrow[r] = lrow[r] * alpha[r] + p0 + p1; // lane-local partial sum
            S[0][r] = p0; S[1][r] = p1;
        }
#pragma unroll
        for (int d = 0; d < 8; d++)
#pragma unroll
            for (int r = 0; r < 4; r++) accO[d][r] *= alpha[r];

        // P: C-layout -> LDS -> A-layout (same-wave round trip)
#pragma unroll
        for (int cb = 0; cb < 2; cb++)
#pragma unroll
            for (int r = 0; r < 4; r++)
                sP[wv][(quad * 4 + r) * 40 + cb * 16 + l16] = (bf16_t)S[cb][r];
        bf16x8 pF = *(const bf16x8*)(&sP[wv][l16 * 40 + quad * 8]);

        // O += P V
#pragma unroll
        for (int d = 0; d < 8; d++) {
            bf16x8 vF = *(const bf16x8*)(&sV[(d * 16 + l16) * 40 + quad * 8]);
            accO[d] = __builtin_amdgcn_mfma_f32_16x16x32_bf16(pF, vF, accO[d], 0, 0, 0);
        }
        __syncthreads();
    }

    // finalize denominators (reduce lane-local partials across the quad)
#pragma unroll
    for (int r = 0; r < 4; r++) {
        float s = lrow[r];
#pragma unroll
        for (int msk = 1; msk < 16; msk <<= 1) s += __shfl_xor(s, msk);
        lrow[r] = 1.0f / s;
    }

    // O = acc/l + q (residual)
#pragma unroll
    for (int d = 0; d < 8; d++) {
#pragma unroll
        for (int r = 0; r < 4; r++) {
            int grow = qrow + quad * 4 + r;
            int gcol = h * DHEAD + d * 16 + l16;
            O[(size_t)grow * DMODEL + gcol] =
                accO[d][r] * lrow[r] + (float)qb[(size_t)grow * DMODEL + gcol];
        }
    }
}

// ---------------------------------------------------------------------------
// LayerNorm over rows of 1024
// ---------------------------------------------------------------------------
__global__ __launch_bounds__(256) void ln_k(
    const float* __restrict__ X, const float* __restrict__ g,
    const float* __restrict__ bta, float* __restrict__ Y)
{
    const int row = blockIdx.x;
    const int t = threadIdx.x;
    float4 x = *(const float4*)(X + (size_t)row * DMODEL + t * 4);
    float s  = x.x + x.y + x.z + x.w;
    float sq = x.x * x.x + x.y * x.y + x.z * x.z + x.w * x.w;
#pragma unroll
    for (int o = 1; o < 64; o <<= 1) {
        s  += __shfl_xor(s, o);
        sq += __shfl_xor(sq, o);
    }
    __shared__ float ls[8];
    int w = t >> 6, ln = t & 63;
    if (ln == 0) { ls[w] = s; ls[4 + w] = sq; }
    __syncthreads();
    s  = ls[0] + ls[1] + ls[2] + ls[3];
    sq = ls[4] + ls[5] + ls[6] + ls[7];
    float mu  = s * (1.f / DMODEL);
    float var = sq * (1.f / DMODEL) - mu * mu;
    float rs  = rsqrtf(var + 1e-5f);
    float4 gv = *(const float4*)(g + t * 4);
    float4 bv = *(const float4*)(bta + t * 4);
    float4 y;
    y.x = (x.x - mu) * rs * gv.x + bv.x;
    y.y = (x.y - mu) * rs * gv.y + bv.y;
    y.z = (x.z - mu) * rs * gv.z + bv.z;
    y.w = (x.w - mu) * rs * gv.w + bv.w;
    *(float4*)(Y + (size_t)row * DMODEL + t * 4) = y;
}

// ---------------------------------------------------------------------------
extern "C" void kernel_launch(void* const* d_in, const int* in_sizes, int n_in,
                              void* d_out, int out_size, void* d_ws, size_t ws_size,
                              hipStream_t stream)
{
    const float* Q  = (const float*)d_in[0];
    const float* Kx = (const float*)d_in[1];
    const float* Wq = (const float*)d_in[2];
    const float* bq = (const float*)d_in[3];
    const float* Wk = (const float*)d_in[4];
    const float* bk = (const float*)d_in[5];
    const float* Wv = (const float*)d_in[6];
    const float* bv = (const float*)d_in[7];
    const float* Wo = (const float*)d_in[8];
    const float* bo = (const float*)d_in[9];
    const float* g0 = (const float*)d_in[10];
    const float* b0 = (const float*)d_in[11];
    const float* g1 = (const float*)d_in[12];
    const float* b1 = (const float*)d_in[13];
    float* out = (float*)d_out;

    char* ws = (char*)d_ws;
    const size_t SZ_BF = (size_t)B_DIM * NQ * DMODEL * sizeof(bf16_t); // 16.8 MB
    const size_t SZ_F  = (size_t)B_DIM * NQ * DMODEL * sizeof(float);  // 33.5 MB
    bf16_t* qb   = (bf16_t*)(ws);
    bf16_t* kb   = (bf16_t*)(ws + SZ_BF);
    bf16_t* vT   = (bf16_t*)(ws + 2 * SZ_BF);
    float*  Obuf = (float*)(ws + 3 * SZ_BF);
    float*  Lf   = (float*)(ws + 3 * SZ_BF + SZ_F);

    const int M = B_DIM * NQ; // 8192
    dim3 gg(DMODEL / 128, M / 128); // (8, 64)

    gemm_nt<0><<<gg, 256, 0, stream>>>(Q,  Wq, bq, nullptr, qb, nullptr, M, DMODEL, DMODEL);
    gemm_nt<0><<<gg, 256, 0, stream>>>(Kx, Wk, bk, nullptr, kb, nullptr, M, DMODEL, DMODEL);
    gemm_nt<2><<<gg, 256, 0, stream>>>(Kx, Wv, bv, nullptr, vT, nullptr, M, DMODEL, DMODEL);

    attn_k<<<dim3(NQ / 64, NH, B_DIM), 256, 0, stream>>>(qb, kb, vT, Obuf);

    ln_k<<<dim3(M), 256, 0, stream>>>(Obuf, g0, b0, Lf);

    gemm_nt<1><<<gg, 256, 0, stream>>>(Lf, Wo, bo, Lf, nullptr, Obuf, M, DMODEL, DMODEL);

    ln_k<<<dim3(M), 256, 0, stream>>>(Obuf, g1, b1, out);
}

// Round 2
// 522.733 us; speedup vs baseline: 1.0862x; 1.0862x over previous
//
#include <hip/hip_runtime.h>
#include <hip/hip_bf16.h>

typedef __bf16 bf16_t;
typedef __bf16 bf16x8 __attribute__((ext_vector_type(8)));
typedef __bf16 bf16x4 __attribute__((ext_vector_type(4)));
typedef float f32x4 __attribute__((ext_vector_type(4)));

#define B_DIM 4
#define NQ 2048
#define NK 2048
#define DMODEL 1024
#define NH 8
#define DHEAD 128

#define AS1 __attribute__((address_space(1)))
#define AS3 __attribute__((address_space(3)))

__device__ __forceinline__ void gl_lds16(const void* g, void* l) {
    __builtin_amdgcn_global_load_lds((const AS1 void*)g, (AS3 void*)l, 16, 0, 0);
}

// ---------------------------------------------------------------------------
// fp32 -> bf16 conversion, 6 pairs selected by blockIdx.y
// ---------------------------------------------------------------------------
struct CvtArgs {
    const float* s[6];
    bf16_t* d[6];
    int n[6];
};

__global__ __launch_bounds__(256) void cvt_k(CvtArgs a) {
    const int p = blockIdx.y;
    const float* s = a.s[p];
    bf16_t* d = a.d[p];
    const int n = a.n[p];
    const int stride = gridDim.x * 256 * 8;
    for (int i = (blockIdx.x * 256 + threadIdx.x) * 8; i < n; i += stride) {
        float4 x0 = *(const float4*)(s + i);
        float4 x1 = *(const float4*)(s + i + 4);
        bf16x8 o = {(bf16_t)x0.x, (bf16_t)x0.y, (bf16_t)x0.z, (bf16_t)x0.w,
                    (bf16_t)x1.x, (bf16_t)x1.y, (bf16_t)x1.z, (bf16_t)x1.w};
        *(bf16x8*)(d + i) = o;
    }
}

// ---------------------------------------------------------------------------
// bf16 GEMM NT: C[M,N] = A[M,K] * B[N,K]^T + bias, global_load_lds staging.
// LDS layout per 32-k tile: issue-blocked [row>>4][kc*16 + row&15][8 elems]
// MODE 0: bf16 out; MODE 1: fp32 out = resid + relu(acc+bias); MODE 2: vT scatter
// ---------------------------------------------------------------------------
template <int MODE>
__global__ __launch_bounds__(256) void gemm_bt(
    const bf16_t* __restrict__ A, const bf16_t* __restrict__ Bw,
    const float* __restrict__ bias, const float* resid,
    bf16_t* __restrict__ Cb, float* Cf, int M, int N, int K)
{
    const int tid  = threadIdx.x;
    const int lane = tid & 63;
    const int wv   = tid >> 6;
    const int l16  = lane & 15;
    const int quad = (lane >> 4) & 3;
    const int kc4  = lane >> 4;
    const int wr   = wv >> 1, wc = wv & 1;
    const int rowBase = blockIdx.y * 128;
    const int colBase = blockIdx.x * 128;

    __shared__ bf16_t sA[4096];   // 8 KB
    __shared__ bf16_t sB[4096];   // 8 KB

    const bf16_t* gA = A + (size_t)(rowBase + wv * 32 + l16) * K + kc4 * 8;
    const bf16_t* gB = Bw + (size_t)(colBase + wv * 32 + l16) * K + kc4 * 8;
    bf16_t* lA0 = &sA[(wv * 2) * 512];
    bf16_t* lA1 = &sA[(wv * 2 + 1) * 512];
    bf16_t* lB0 = &sB[(wv * 2) * 512];
    bf16_t* lB1 = &sB[(wv * 2 + 1) * 512];

    const f32x4 fz = {0.f, 0.f, 0.f, 0.f};
    f32x4 acc[4][4];
#pragma unroll
    for (int i = 0; i < 4; i++)
#pragma unroll
        for (int j = 0; j < 4; j++) acc[i][j] = fz;

    for (int k0 = 0; k0 < K; k0 += 32) {
        gl_lds16(gA, lA0);
        gl_lds16(gA + (size_t)16 * K, lA1);
        gl_lds16(gB, lB0);
        gl_lds16(gB + (size_t)16 * K, lB1);
        gA += 32; gB += 32;
        __syncthreads();

        bf16x8 aF[4], bF[4];
#pragma unroll
        for (int mi = 0; mi < 4; mi++)
            aF[mi] = *(const bf16x8*)(&sA[(wr * 4 + mi) * 512 + (quad * 16 + l16) * 8]);
#pragma unroll
        for (int ni = 0; ni < 4; ni++)
            bF[ni] = *(const bf16x8*)(&sB[(wc * 4 + ni) * 512 + (quad * 16 + l16) * 8]);
#pragma unroll
        for (int mi = 0; mi < 4; mi++)
#pragma unroll
            for (int ni = 0; ni < 4; ni++)
                acc[mi][ni] = __builtin_amdgcn_mfma_f32_16x16x32_bf16(
                    aF[mi], bF[ni], acc[mi][ni], 0, 0, 0);
        __syncthreads();
    }

#pragma unroll
    for (int mi = 0; mi < 4; mi++) {
#pragma unroll
        for (int ni = 0; ni < 4; ni++) {
            int row0 = rowBase + wr * 64 + mi * 16 + quad * 4;
            int col  = colBase + wc * 64 + ni * 16 + l16;
            float bv = bias[col];
            if (MODE == 0) {
#pragma unroll
                for (int r = 0; r < 4; r++)
                    Cb[(size_t)(row0 + r) * N + col] = (bf16_t)(acc[mi][ni][r] + bv);
            } else if (MODE == 1) {
#pragma unroll
                for (int r = 0; r < 4; r++) {
                    float v = acc[mi][ni][r] + bv;
                    v = v > 0.f ? v : 0.f;
                    Cf[(size_t)(row0 + r) * N + col] =
                        resid[(size_t)(row0 + r) * N + col] + v;
                }
            } else {
                int b  = row0 >> 11;
                int n0 = row0 & 2047;
                int hh = col >> 7;
                int dd = col & 127;
                bf16x4 p = {(bf16_t)(acc[mi][ni][0] + bv), (bf16_t)(acc[mi][ni][1] + bv),
                            (bf16_t)(acc[mi][ni][2] + bv), (bf16_t)(acc[mi][ni][3] + bv)};
                *(bf16x4*)(Cb + (size_t)((b * NH + hh) * DHEAD + dd) * NK + n0) = p;
            }
        }
    }
}

// ---------------------------------------------------------------------------
// Flash attention: O = q + softmax(q k^T / sqrt(d)) v
// 256 thr = 4 waves; wave owns 32 q-rows (2 frags); 128 q-rows/block; 64-key tiles
// ---------------------------------------------------------------------------
__global__ __launch_bounds__(256) void attn_k(
    const bf16_t* __restrict__ qb, const bf16_t* __restrict__ kb,
    const bf16_t* __restrict__ vT, float* __restrict__ O)
{
    const int tid  = threadIdx.x;
    const int lane = tid & 63;
    const int wv   = tid >> 6;
    const int l16  = lane & 15;
    const int quad = (lane >> 4) & 3;
    const int kc4  = lane >> 4;
    const int qt   = blockIdx.x * 128;
    const int h    = blockIdx.y;
    const int b    = blockIdx.z;
    const int bh   = b * NH + h;

    __shared__ bf16_t sK[8192];          // 64 keys x 128 d, issue-blocked, 16 KB
    __shared__ bf16_t sV[8192];          // 128 d x 64 keys, issue-blocked, 16 KB
    __shared__ unsigned sPd[4][1152];    // per-wave P: 32 rows x 36 dwords, 18 KB

    const int qrow0 = b * NQ + qt + wv * 32;
    bf16x8 qF[2][4];
#pragma unroll
    for (int rf = 0; rf < 2; rf++)
#pragma unroll
        for (int c = 0; c < 4; c++)
            qF[rf][c] = *(const bf16x8*)(qb + (size_t)(qrow0 + rf * 16 + l16) * DMODEL +
                                         h * DHEAD + c * 32 + quad * 8);

    const f32x4 fz = {0.f, 0.f, 0.f, 0.f};
    f32x4 accO[2][8];
#pragma unroll
    for (int rf = 0; rf < 2; rf++)
#pragma unroll
        for (int d = 0; d < 8; d++) accO[rf][d] = fz;
    float mrow[2][4], lrow[2][4];
#pragma unroll
    for (int rf = 0; rf < 2; rf++)
#pragma unroll
        for (int r = 0; r < 4; r++) { mrow[rf][r] = -3e38f; lrow[rf][r] = 0.f; }
    const float SC = 0.08838834764831845f;  // 1/sqrt(128)

    const bf16_t* gK = kb + (size_t)(b * NK + wv * 16 + l16) * DMODEL + h * DHEAD + kc4 * 8;
    const bf16_t* gV = vT + (size_t)(bh * DHEAD + wv * 32 + l16) * NK + kc4 * 8;
    const bool wlane = ((l16 & 1) == 0);

    for (int kt = 0; kt < NK; kt += 64) {
        // stage K tile (4 issues/wave) and V tile (4 issues/wave)
#pragma unroll
        for (int s = 0; s < 4; s++)
            gl_lds16(gK + (size_t)kt * DMODEL + s * 32, &sK[(wv * 4 + s) * 512]);
#pragma unroll
        for (int i = 0; i < 2; i++)
#pragma unroll
            for (int kh = 0; kh < 2; kh++)
                gl_lds16(gV + (size_t)i * 16 * NK + kt + kh * 32,
                         &sV[((wv * 2 + i) * 2 + kh) * 512]);
        __syncthreads();

        // S = q k^T (raw logits)
        f32x4 S[2][4];
#pragma unroll
        for (int rf = 0; rf < 2; rf++)
#pragma unroll
            for (int cb = 0; cb < 4; cb++) S[rf][cb] = fz;
#pragma unroll
        for (int cb = 0; cb < 4; cb++)
#pragma unroll
            for (int c = 0; c < 4; c++) {
                bf16x8 kF = *(const bf16x8*)(&sK[(cb * 4 + c) * 512 + (quad * 16 + l16) * 8]);
                S[0][cb] = __builtin_amdgcn_mfma_f32_16x16x32_bf16(qF[0][c], kF, S[0][cb], 0, 0, 0);
                S[1][cb] = __builtin_amdgcn_mfma_f32_16x16x32_bf16(qF[1][c], kF, S[1][cb], 0, 0, 0);
            }

        // online softmax (scale folded into exp args)
        float alph[2][4];
#pragma unroll
        for (int rf = 0; rf < 2; rf++)
#pragma unroll
            for (int r = 0; r < 4; r++) {
                float mx = fmaxf(fmaxf(S[rf][0][r], S[rf][1][r]),
                                 fmaxf(S[rf][2][r], S[rf][3][r]));
                mx = fmaxf(mx, __shfl_xor(mx, 1));
                mx = fmaxf(mx, __shfl_xor(mx, 2));
                mx = fmaxf(mx, __shfl_xor(mx, 4));
                mx = fmaxf(mx, __shfl_xor(mx, 8));
                float mn = fmaxf(mrow[rf][r], mx);
                float al = __expf((mrow[rf][r] - mn) * SC);
                mrow[rf][r] = mn;
                float mc = mn * SC;
                float p0 = __expf(fmaf(S[rf][0][r], SC, -mc));
                float p1 = __expf(fmaf(S[rf][1][r], SC, -mc));
                float p2 = __expf(fmaf(S[rf][2][r], SC, -mc));
                float p3 = __expf(fmaf(S[rf][3][r], SC, -mc));
                S[rf][0][r] = p0; S[rf][1][r] = p1; S[rf][2][r] = p2; S[rf][3][r] = p3;
                lrow[rf][r] = lrow[rf][r] * al + ((p0 + p1) + (p2 + p3));
                alph[rf][r] = al;
            }
#pragma unroll
        for (int rf = 0; rf < 2; rf++)
#pragma unroll
            for (int d = 0; d < 8; d++)
#pragma unroll
                for (int r = 0; r < 4; r++) accO[rf][d][r] *= alph[rf][r];

        // P: C-layout -> packed bf16-pair dwords in LDS (conflict-free writes)
#pragma unroll
        for (int rf = 0; rf < 2; rf++)
#pragma unroll
            for (int cb = 0; cb < 4; cb++)
#pragma unroll
                for (int r = 0; r < 4; r++) {
                    unsigned u = (unsigned)__builtin_bit_cast(unsigned short, (bf16_t)S[rf][cb][r]);
                    unsigned o = __shfl_xor(u, 1);
                    if (wlane)
                        sPd[wv][(rf * 16 + quad * 4 + r) * 36 + cb * 8 + (l16 >> 1)] = u | (o << 16);
                }

        // O += P V
#pragma unroll
        for (int kc = 0; kc < 2; kc++) {
            bf16x8 pF0 = *(const bf16x8*)(&sPd[wv][(l16) * 36 + kc * 16 + quad * 4]);
            bf16x8 pF1 = *(const bf16x8*)(&sPd[wv][(16 + l16) * 36 + kc * 16 + quad * 4]);
#pragma unroll
            for (int db = 0; db < 8; db++) {
                bf16x8 vF = *(const bf16x8*)(&sV[(db * 2 + kc) * 512 + (quad * 16 + l16) * 8]);
                accO[0][db] = __builtin_amdgcn_mfma_f32_16x16x32_bf16(pF0, vF, accO[0][db], 0, 0, 0);
                accO[1][db] = __builtin_amdgcn_mfma_f32_16x16x32_bf16(pF1, vF, accO[1][db], 0, 0, 0);
            }
        }
        __syncthreads();
    }

    // finalize denominators
    float inv[2][4];
#pragma unroll
    for (int rf = 0; rf < 2; rf++)
#pragma unroll
        for (int r = 0; r < 4; r++) {
            float s = lrow[rf][r];
            s += __shfl_xor(s, 1);
            s += __shfl_xor(s, 2);
            s += __shfl_xor(s, 4);
            s += __shfl_xor(s, 8);
            inv[rf][r] = 1.0f / s;
        }

    // O = acc/l + q residual
#pragma unroll
    for (int rf = 0; rf < 2; rf++)
#pragma unroll
        for (int d = 0; d < 8; d++)
#pragma unroll
            for (int r = 0; r < 4; r++) {
                int grow = qrow0 + rf * 16 + quad * 4 + r;
                int gcol = h * DHEAD + d * 16 + l16;
                O[(size_t)grow * DMODEL + gcol] =
                    accO[rf][d][r] * inv[rf][r] + (float)qb[(size_t)grow * DMODEL + gcol];
            }
}

// ---------------------------------------------------------------------------
// LayerNorm over rows of 1024; optional extra bf16 output
// ---------------------------------------------------------------------------
__global__ __launch_bounds__(256) void ln_k(
    const float* __restrict__ X, const float* __restrict__ g,
    const float* __restrict__ bta, float* __restrict__ Yf, bf16_t* Yb)
{
    const int row = blockIdx.x;
    const int t = threadIdx.x;
    float4 x = *(const float4*)(X + (size_t)row * DMODEL + t * 4);
    float s  = x.x + x.y + x.z + x.w;
    float sq = x.x * x.x + x.y * x.y + x.z * x.z + x.w * x.w;
#pragma unroll
    for (int o = 1; o < 64; o <<= 1) {
        s  += __shfl_xor(s, o);
        sq += __shfl_xor(sq, o);
    }
    __shared__ float ls[8];
    int w = t >> 6, ln = t & 63;
    if (ln == 0) { ls[w] = s; ls[4 + w] = sq; }
    __syncthreads();
    s  = ls[0] + ls[1] + ls[2] + ls[3];
    sq = ls[4] + ls[5] + ls[6] + ls[7];
    float mu  = s * (1.f / DMODEL);
    float var = sq * (1.f / DMODEL) - mu * mu;
    float rs  = rsqrtf(var + 1e-5f);
    float4 gv = *(const float4*)(g + t * 4);
    float4 bv = *(const float4*)(bta + t * 4);
    float4 y;
    y.x = (x.x - mu) * rs * gv.x + bv.x;
    y.y = (x.y - mu) * rs * gv.y + bv.y;
    y.z = (x.z - mu) * rs * gv.z + bv.z;
    y.w = (x.w - mu) * rs * gv.w + bv.w;
    *(float4*)(Yf + (size_t)row * DMODEL + t * 4) = y;
    if (Yb) {
        bf16x4 yb = {(bf16_t)y.x, (bf16_t)y.y, (bf16_t)y.z, (bf16_t)y.w};
        *(bf16x4*)(Yb + (size_t)row * DMODEL + t * 4) = yb;
    }
}

// ---------------------------------------------------------------------------
extern "C" void kernel_launch(void* const* d_in, const int* in_sizes, int n_in,
                              void* d_out, int out_size, void* d_ws, size_t ws_size,
                              hipStream_t stream)
{
    const float* Q  = (const float*)d_in[0];
    const float* Kx = (const float*)d_in[1];
    const float* Wq = (const float*)d_in[2];
    const float* bq = (const float*)d_in[3];
    const float* Wk = (const float*)d_in[4];
    const float* bk = (const float*)d_in[5];
    const float* Wv = (const float*)d_in[6];
    const float* bv = (const float*)d_in[7];
    const float* Wo = (const float*)d_in[8];
    const float* bo = (const float*)d_in[9];
    const float* g0 = (const float*)d_in[10];
    const float* b0 = (const float*)d_in[11];
    const float* g1 = (const float*)d_in[12];
    const float* b1 = (const float*)d_in[13];
    float* out = (float*)d_out;

    char* ws = (char*)d_ws;
    // layout (bytes):
    bf16_t* Qc  = (bf16_t*)(ws);                  // 16,777,216
    bf16_t* Kc  = (bf16_t*)(ws + 16777216);       // 16,777,216
    bf16_t* Wqc = (bf16_t*)(ws + 33554432);       // 2,097,152
    bf16_t* Wkc = (bf16_t*)(ws + 35651584);
    bf16_t* Wvc = (bf16_t*)(ws + 37748736);
    bf16_t* Woc = (bf16_t*)(ws + 39845888);
    bf16_t* qbb = (bf16_t*)(ws + 41943040);       // 16,777,216
    bf16_t* kbb = (bf16_t*)(ws + 58720256);       // 16,777,216
    bf16_t* vT  = (bf16_t*)(ws + 75497472);       // 16,777,216
    float*  Obuf = (float*)(ws + 92274688);       // 33,554,432  (ends 125,829,120)
    float*  Lf  = (float*)(ws);                   // alias Qc+Kc (dead after gemm-v)
    bf16_t* Lb  = kbb;                            // alias kb (dead after attn)

    CvtArgs ca;
    ca.s[0] = Q;  ca.d[0] = Qc;  ca.n[0] = B_DIM * NQ * DMODEL;
    ca.s[1] = Kx; ca.d[1] = Kc;  ca.n[1] = B_DIM * NK * DMODEL;
    ca.s[2] = Wq; ca.d[2] = Wqc; ca.n[2] = DMODEL * DMODEL;
    ca.s[3] = Wk; ca.d[3] = Wkc; ca.n[3] = DMODEL * DMODEL;
    ca.s[4] = Wv; ca.d[4] = Wvc; ca.n[4] = DMODEL * DMODEL;
    ca.s[5] = Wo; ca.d[5] = Woc; ca.n[5] = DMODEL * DMODEL;
    cvt_k<<<dim3(512, 6), 256, 0, stream>>>(ca);

    const int M = B_DIM * NQ;  // 8192
    dim3 gg(DMODEL / 128, M / 128);  // (8, 64)

    gemm_bt<0><<<gg, 256, 0, stream>>>(Qc, Wqc, bq, nullptr, qbb, nullptr, M, DMODEL, DMODEL);
    gemm_bt<0><<<gg, 256, 0, stream>>>(Kc, Wkc, bk, nullptr, kbb, nullptr, M, DMODEL, DMODEL);
    gemm_bt<2><<<gg, 256, 0, stream>>>(Kc, Wvc, bv, nullptr, vT, nullptr, M, DMODEL, DMODEL);

    attn_k<<<dim3(NQ / 128, NH, B_DIM), 256, 0, stream>>>(qbb, kbb, vT, Obuf);

    ln_k<<<dim3(M), 256, 0, stream>>>(Obuf, g0, b0, Lf, Lb);

    gemm_bt<1><<<gg, 256, 0, stream>>>(Lb, Woc, bo, Lf, nullptr, Lf, M, DMODEL, DMODEL);

    ln_k<<<dim3(M), 256, 0, stream>>>(Lf, g1, b1, out, nullptr);
}